// Round 1
// baseline (344.215 us; speedup 1.0000x reference)
//
#include <hip/hip_runtime.h>

#define NN 50000
#define NE 800000
#define D  128
#define TR 32   // rows per tile in the fused kernel

// ---------------------------------------------------------------------------
// Key algebraic reduction (verified against reference semantics):
//   attended = weights * v[tgt]; agg = segment_sum(attended, tgt)
//   => agg[n] = v[n] * (sum of softmax weights in segment n) = v[n] (or 0 if
//      node n has no incoming edge). So:
//   out_row = nodes + bo + mask * (nodes @ (Wv@Wo) + bv@Wo), then LayerNorm.
// ---------------------------------------------------------------------------

// ws layout: Wc[128*128] floats | bc[128] floats | mask[NN] ints

__global__ __launch_bounds__(256) void prep_kernel(
    const float* __restrict__ Wv, const float* __restrict__ bv,
    const float* __restrict__ Wo,
    float* __restrict__ Wc, float* __restrict__ bc, int* __restrict__ mask)
{
    int b = blockIdx.x, t = threadIdx.x;
    if (b < 64) {
        // W_comb[k][j] = sum_m Wv[k][m] * Wo[m][j]; 2 rows per block
        int k = 2 * b + (t >> 7);
        int j = t & 127;
        float acc = 0.f;
        #pragma unroll 4
        for (int m = 0; m < 128; ++m)
            acc = fmaf(Wv[k * 128 + m], Wo[m * 128 + j], acc);
        Wc[k * 128 + j] = acc;
    } else if (b == 64) {
        if (t < 128) {
            float acc = 0.f;
            #pragma unroll 4
            for (int m = 0; m < 128; ++m)
                acc = fmaf(bv[m], Wo[m * 128 + t], acc);
            bc[t] = acc;
        }
    } else {
        int i = (b - 65) * 256 + t;
        if (i < NN) mask[i] = 0;
    }
}

__global__ __launch_bounds__(256) void scatter_kernel(
    const int* __restrict__ tgt, int* __restrict__ mask)
{
    int e = blockIdx.x * 256 + threadIdx.x;
    if (e < NE) mask[tgt[e]] = 1;   // benign race: all writers store 1
}

__global__ __launch_bounds__(256, 3) void fused_kernel(
    const float* __restrict__ nodes,
    const float* __restrict__ Wc, const float* __restrict__ bc,
    const int* __restrict__ mask,
    const float* __restrict__ bo,
    const float* __restrict__ gamma, const float* __restrict__ beta,
    float* __restrict__ out)
{
    __shared__ float Wl[64 * 128];    // 32 KB: one K-half of W_comb
    __shared__ float Ndl[TR * 128];   // 16 KB: node tile
    __shared__ int   Ml[TR];

    const int tid  = threadIdx.x;
    const int cg   = tid & 31;    // column group: cols 4*cg .. 4*cg+3
    const int slot = tid >> 5;    // 0..7, rows slot*4 .. slot*4+3
    const int rbase = slot * 4;

    const float4 bo4 = ((const float4*)bo)[cg];
    const float4 bc4 = ((const float4*)bc)[cg];
    const float4 g4  = ((const float4*)gamma)[cg];
    const float4 be4 = ((const float4*)beta)[cg];

    const int ntiles = (NN + TR - 1) / TR;
    for (int tile = blockIdx.x; tile < ntiles; tile += gridDim.x) {
        const int r0 = tile * TR;
        __syncthreads();  // protect Ndl/Wl against previous iteration's reads

        // stage node tile: 32 rows x 128 cols = 1024 float4
        #pragma unroll
        for (int i = 0; i < 4; ++i) {
            int f  = tid + 256 * i;
            int rr = f >> 5, cc = f & 31;
            int gr = r0 + rr;
            float4 v = make_float4(0.f, 0.f, 0.f, 0.f);
            if (gr < NN) v = ((const float4*)nodes)[gr * 32 + cc];
            ((float4*)Ndl)[f] = v;
        }
        if (tid < TR) {
            int gr = r0 + tid;
            Ml[tid] = (gr < NN) ? mask[gr] : 0;
        }

        float4 acc[4];
        acc[0] = acc[1] = acc[2] = acc[3] = make_float4(0.f, 0.f, 0.f, 0.f);

        #pragma unroll
        for (int h = 0; h < 2; ++h) {
            if (h) __syncthreads();  // previous half's compute must finish
            const float4* Wsrc = (const float4*)(Wc + h * 64 * 128);
            #pragma unroll
            for (int i = 0; i < 8; ++i)
                ((float4*)Wl)[tid + 256 * i] = Wsrc[tid + 256 * i];
            __syncthreads();

            #pragma unroll 2
            for (int k4 = 0; k4 < 16; ++k4) {
                const float4* wr = (const float4*)(Wl + k4 * 4 * 128);
                float4 w0 = wr[cg];
                float4 w1 = wr[32 + cg];
                float4 w2 = wr[64 + cg];
                float4 w3 = wr[96 + cg];
                #pragma unroll
                for (int rr = 0; rr < 4; ++rr) {
                    float4 nv = ((const float4*)(Ndl + (rbase + rr) * 128))[h * 16 + k4];
                    acc[rr].x = fmaf(nv.x, w0.x, acc[rr].x);
                    acc[rr].x = fmaf(nv.y, w1.x, acc[rr].x);
                    acc[rr].x = fmaf(nv.z, w2.x, acc[rr].x);
                    acc[rr].x = fmaf(nv.w, w3.x, acc[rr].x);
                    acc[rr].y = fmaf(nv.x, w0.y, acc[rr].y);
                    acc[rr].y = fmaf(nv.y, w1.y, acc[rr].y);
                    acc[rr].y = fmaf(nv.z, w2.y, acc[rr].y);
                    acc[rr].y = fmaf(nv.w, w3.y, acc[rr].y);
                    acc[rr].z = fmaf(nv.x, w0.z, acc[rr].z);
                    acc[rr].z = fmaf(nv.y, w1.z, acc[rr].z);
                    acc[rr].z = fmaf(nv.z, w2.z, acc[rr].z);
                    acc[rr].z = fmaf(nv.w, w3.z, acc[rr].z);
                    acc[rr].w = fmaf(nv.x, w0.w, acc[rr].w);
                    acc[rr].w = fmaf(nv.y, w1.w, acc[rr].w);
                    acc[rr].w = fmaf(nv.z, w2.w, acc[rr].w);
                    acc[rr].w = fmaf(nv.w, w3.w, acc[rr].w);
                }
            }
        }

        // epilogue: residual + bias + mask, LayerNorm across 128 cols
        #pragma unroll
        for (int rr = 0; rr < 4; ++rr) {
            int r = r0 + rbase + rr;
            float4 nd = ((const float4*)(Ndl + (rbase + rr) * 128))[cg];
            float m = (Ml[rbase + rr] != 0) ? 1.f : 0.f;
            float4 x;
            x.x = nd.x + bo4.x + m * (acc[rr].x + bc4.x);
            x.y = nd.y + bo4.y + m * (acc[rr].y + bc4.y);
            x.z = nd.z + bo4.z + m * (acc[rr].z + bc4.z);
            x.w = nd.w + bo4.w + m * (acc[rr].w + bc4.w);

            float s  = x.x + x.y + x.z + x.w;
            float ss = x.x * x.x + x.y * x.y + x.z * x.z + x.w * x.w;
            #pragma unroll
            for (int off = 1; off < 32; off <<= 1) {
                s  += __shfl_xor(s, off);
                ss += __shfl_xor(ss, off);
            }
            float mu   = s * (1.f / 128.f);
            float var  = ss * (1.f / 128.f) - mu * mu;
            float rstd = rsqrtf(var + 1e-5f);

            float4 o;
            o.x = (x.x - mu) * rstd * g4.x + be4.x;
            o.y = (x.y - mu) * rstd * g4.y + be4.y;
            o.z = (x.z - mu) * rstd * g4.z + be4.z;
            o.w = (x.w - mu) * rstd * g4.w + be4.w;
            if (r < NN) ((float4*)out)[r * 32 + cg] = o;
        }
    }
}

extern "C" void kernel_launch(void* const* d_in, const int* in_sizes, int n_in,
                              void* d_out, int out_size, void* d_ws, size_t ws_size,
                              hipStream_t stream) {
    const float* nodes = (const float*)d_in[0];
    const int*   ei    = (const int*)d_in[2];
    const float* Wv    = (const float*)d_in[9];
    const float* bv    = (const float*)d_in[10];
    const float* Wo    = (const float*)d_in[21];
    const float* bo    = (const float*)d_in[22];
    const float* gamma = (const float*)d_in[23];
    const float* beta  = (const float*)d_in[24];

    float* Wc   = (float*)d_ws;          // 16384 floats
    float* bc   = Wc + 16384;            // 128 floats
    int*   mask = (int*)(bc + 128);      // NN ints

    prep_kernel<<<65 + (NN + 255) / 256, 256, 0, stream>>>(Wv, bv, Wo, Wc, bc, mask);
    scatter_kernel<<<(NE + 255) / 256, 256, 0, stream>>>(ei + NE, mask);
    fused_kernel<<<768, 256, 0, stream>>>(nodes, Wc, bc, mask, bo, gamma, beta,
                                          (float*)d_out);
}